// Round 2
// baseline (792.593 us; speedup 1.0000x reference)
//
#include <hip/hip_runtime.h>
#include <hip/hip_bf16.h>

// ---------------------------------------------------------------------------
// HINormer forward (gh path only; the r/re_conv chain is dead code w.r.t. the
// returned outputs).
//
//   gh0[n]   = x[n] @ fcW[type[n]] + fcB[type[n]]
//   deg[c]   = 1 + #{e : col[e] == c}          (self-loop included)
//   dis[n]   = deg[n]^-0.5
//   per layer l:
//     xws[n]  = (gh @ gcnW[l])[n] * dis[n]
//     acc[c]  = xws[c] + sum_{e: col[e]=c} xws[row[e]]
//     gh[n]   = relu(acc[n]*dis[n] + gcnB[l])
//   out0[b]  = gh[seqs[b,0]] @ predW + predB
//   out1[b]  = (float)label[seqs[b,0]]
// ---------------------------------------------------------------------------

#define NPB 32  // nodes per block in GEMM-ish kernels

__global__ __launch_bounds__(256) void k_fc(const float* __restrict__ x,
                                            const int* __restrict__ node_type,
                                            const float* __restrict__ fcW,
                                            const float* __restrict__ fcB,
                                            float* __restrict__ gh, int n_nodes) {
  __shared__ float xs[NPB * 128];   // 16 KB
  __shared__ float Ws[128 * 128];   // 64 KB
  const int t = threadIdx.x;
  const int nbase = blockIdx.x * NPB;
  const int nend = min(nbase + NPB, n_nodes);

  // load x tile (coalesced)
  for (int k = 0; k < 16; ++k) {
    int idx = k * 256 + t;
    int node = nbase + (idx >> 7);
    xs[idx] = (node < n_nodes) ? x[(size_t)nbase * 128 + idx] : 0.0f;
  }
  const int t0 = node_type[nbase];
  const int t1 = node_type[nend - 1];
  const bool uniform = (t0 == t1);  // node_type is sorted
  if (uniform) {
    const float* W = fcW + (size_t)t0 * 128 * 128;
    for (int k = 0; k < 64; ++k) {
      int idx = k * 256 + t;
      Ws[idx] = W[idx];
    }
  }
  __syncthreads();

  const int dq = (t & 31) * 4;  // output quad
  const int g = t >> 5;         // 0..7  -> nodes g, g+8, g+16, g+24
  if (uniform) {
    float4 bias = *reinterpret_cast<const float4*>(fcB + (size_t)t0 * 128 + dq);
    float4 acc[4];
#pragma unroll
    for (int k = 0; k < 4; ++k) acc[k] = bias;
#pragma unroll 8
    for (int i = 0; i < 128; ++i) {
      float4 w = *reinterpret_cast<const float4*>(&Ws[i * 128 + dq]);
#pragma unroll
      for (int k = 0; k < 4; ++k) {
        float xv = xs[(g + 8 * k) * 128 + i];
        acc[k].x += xv * w.x; acc[k].y += xv * w.y;
        acc[k].z += xv * w.z; acc[k].w += xv * w.w;
      }
    }
#pragma unroll
    for (int k = 0; k < 4; ++k) {
      int node = nbase + g + 8 * k;
      if (node < n_nodes)
        *reinterpret_cast<float4*>(gh + (size_t)node * 128 + dq) = acc[k];
    }
  } else {
    // rare: type boundary inside tile (<= T-1 = 3 blocks total)
    for (int k = 0; k < 4; ++k) {
      int node = nbase + g + 8 * k;
      if (node >= n_nodes) continue;
      int tn = node_type[node];
      const float* W = fcW + (size_t)tn * 128 * 128;
      float4 acc = *reinterpret_cast<const float4*>(fcB + (size_t)tn * 128 + dq);
      for (int i = 0; i < 128; ++i) {
        float4 w = *reinterpret_cast<const float4*>(W + i * 128 + dq);
        float xv = xs[(g + 8 * k) * 128 + i];
        acc.x += xv * w.x; acc.y += xv * w.y;
        acc.z += xv * w.z; acc.w += xv * w.w;
      }
      *reinterpret_cast<float4*>(gh + (size_t)node * 128 + dq) = acc;
    }
  }
}

__global__ __launch_bounds__(256) void k_gemm_scale(const float* __restrict__ hin,
                                                    const float* __restrict__ W,
                                                    const float* __restrict__ dis,
                                                    float* __restrict__ xws,
                                                    float* __restrict__ acc_out,
                                                    int n_nodes) {
  __shared__ float xs[NPB * 128];
  __shared__ float Ws[128 * 128];
  const int t = threadIdx.x;
  const int nbase = blockIdx.x * NPB;

  for (int k = 0; k < 16; ++k) {
    int idx = k * 256 + t;
    int node = nbase + (idx >> 7);
    xs[idx] = (node < n_nodes) ? hin[(size_t)nbase * 128 + idx] : 0.0f;
  }
  for (int k = 0; k < 64; ++k) {
    int idx = k * 256 + t;
    Ws[idx] = W[idx];
  }
  __syncthreads();

  const int dq = (t & 31) * 4;
  const int g = t >> 5;
  float4 acc[4];
#pragma unroll
  for (int k = 0; k < 4; ++k) acc[k] = make_float4(0.f, 0.f, 0.f, 0.f);
#pragma unroll 8
  for (int i = 0; i < 128; ++i) {
    float4 w = *reinterpret_cast<const float4*>(&Ws[i * 128 + dq]);
#pragma unroll
    for (int k = 0; k < 4; ++k) {
      float xv = xs[(g + 8 * k) * 128 + i];
      acc[k].x += xv * w.x; acc[k].y += xv * w.y;
      acc[k].z += xv * w.z; acc[k].w += xv * w.w;
    }
  }
#pragma unroll
  for (int k = 0; k < 4; ++k) {
    int node = nbase + g + 8 * k;
    if (node < n_nodes) {
      float s = dis[node];
      float4 v = make_float4(acc[k].x * s, acc[k].y * s, acc[k].z * s, acc[k].w * s);
      *reinterpret_cast<float4*>(xws + (size_t)node * 128 + dq) = v;
      *reinterpret_cast<float4*>(acc_out + (size_t)node * 128 + dq) = v;  // self-loop init
    }
  }
}

__global__ void k_deg_init(int* __restrict__ deg, int n) {
  int i = blockIdx.x * 256 + threadIdx.x;
  if (i < n) deg[i] = 1;  // self loop
}

__global__ void k_deg_count(const int* __restrict__ col, int* __restrict__ deg, int e) {
  int i = blockIdx.x * 256 + threadIdx.x;
  if (i < e) atomicAdd(&deg[col[i]], 1);
}

__global__ void k_dis(const int* __restrict__ deg, float* __restrict__ dis, int n) {
  int i = blockIdx.x * 256 + threadIdx.x;
  if (i < n) dis[i] = rsqrtf((float)deg[i]);
}

__global__ __launch_bounds__(256) void k_scatter(const int* __restrict__ row,
                                                 const int* __restrict__ col,
                                                 const float* __restrict__ xws,
                                                 float* __restrict__ acc, int e_edges) {
  long tid = (long)blockIdx.x * 256 + threadIdx.x;
  int e = (int)(tid >> 7);
  if (e >= e_edges) return;
  int d = (int)(tid & 127);
  int r = row[e], c = col[e];
  unsafeAtomicAdd(&acc[(size_t)c * 128 + d], xws[(size_t)r * 128 + d]);
}

__global__ void k_finalize(const float* __restrict__ acc, const float* __restrict__ dis,
                           const float* __restrict__ bias, float* __restrict__ gh,
                           int n_nodes) {
  long tid = (long)blockIdx.x * 256 + threadIdx.x;
  int n = (int)(tid >> 7);
  if (n >= n_nodes) return;
  int d = (int)(tid & 127);
  float v = acc[tid] * dis[n] + bias[d];
  gh[tid] = fmaxf(v, 0.0f);
}

__global__ void k_pred(const float* __restrict__ gh, const int* __restrict__ seqs,
                       const int* __restrict__ label, const float* __restrict__ predW,
                       const float* __restrict__ predB, float* __restrict__ out,
                       float* __restrict__ out_label, int b_total, int n_classes,
                       int slen) {
  int tid = blockIdx.x * 256 + threadIdx.x;
  int b = tid / n_classes;
  if (b >= b_total) return;
  int c = tid - b * n_classes;
  int ego = seqs[(size_t)b * slen];
  const float* g = gh + (size_t)ego * 128;
  float s = predB[c];
#pragma unroll 8
  for (int i = 0; i < 128; ++i) s += g[i] * predW[i * n_classes + c];
  out[(size_t)b * n_classes + c] = s;
  if (c == 0) out_label[b] = (float)label[ego];
}

extern "C" void kernel_launch(void* const* d_in, const int* in_sizes, int n_in,
                              void* d_out, int out_size, void* d_ws, size_t ws_size,
                              hipStream_t stream) {
  const float* x        = (const float*)d_in[0];
  const int*   label    = (const int*)d_in[1];
  const int*   seqs     = (const int*)d_in[2];
  const int*   edge     = (const int*)d_in[3];
  const int*   ntype    = (const int*)d_in[4];
  const float* fcW      = (const float*)d_in[5];
  const float* fcB      = (const float*)d_in[6];
  const float* gcnW     = (const float*)d_in[7];
  const float* gcnB     = (const float*)d_in[8];
  // d_in[9..11] = reW / re_wtype / reB : dead code w.r.t. outputs
  const float* predW    = (const float*)d_in[12];
  const float* predB    = (const float*)d_in[13];

  const int n = in_sizes[0] / 128;        // 50000
  const int e = in_sizes[3] / 2;          // 600000
  const int L = in_sizes[8] / 128;        // 2
  const int C = in_sizes[13];             // 16
  const int slen = 16;
  const int b_total = in_sizes[2] / slen; // 2048

  const int* row = edge;
  const int* col = edge + e;

  char* ws = (char*)d_ws;
  const size_t node_mat = (size_t)n * 128 * sizeof(float);
  float* gh   = (float*)ws;
  float* xws  = (float*)(ws + node_mat);
  float* acc  = (float*)(ws + 2 * node_mat);
  float* dis  = (float*)(ws + 3 * node_mat);
  int*   deg  = (int*)(ws + 3 * node_mat + (size_t)n * sizeof(float));

  float* out_logits = (float*)d_out;
  float* out_label  = out_logits + (size_t)b_total * C;

  const int nb = (n + NPB - 1) / NPB;

  hipLaunchKernelGGL(k_fc, dim3(nb), dim3(256), 0, stream, x, ntype, fcW, fcB, gh, n);
  hipLaunchKernelGGL(k_deg_init, dim3((n + 255) / 256), dim3(256), 0, stream, deg, n);
  hipLaunchKernelGGL(k_deg_count, dim3((e + 255) / 256), dim3(256), 0, stream, col, deg, e);
  hipLaunchKernelGGL(k_dis, dim3((n + 255) / 256), dim3(256), 0, stream, deg, dis, n);

  for (int l = 0; l < L; ++l) {
    hipLaunchKernelGGL(k_gemm_scale, dim3(nb), dim3(256), 0, stream,
                       gh, gcnW + (size_t)l * 128 * 128, dis, xws, acc, n);
    long total = (long)e * 128;
    hipLaunchKernelGGL(k_scatter, dim3((unsigned)((total + 255) / 256)), dim3(256), 0,
                       stream, row, col, xws, acc, e);
    hipLaunchKernelGGL(k_finalize, dim3((unsigned)(((long)n * 128 + 255) / 256)),
                       dim3(256), 0, stream, acc, dis, gcnB + (size_t)l * 128, gh, n);
  }
  hipLaunchKernelGGL(k_pred, dim3((b_total * C + 255) / 256), dim3(256), 0, stream,
                     gh, seqs, label, predW, predB, out_logits, out_label,
                     b_total, C, slen);
}

// Round 3
// 390.680 us; speedup vs baseline: 2.0288x; 2.0288x over previous
//
#include <hip/hip_runtime.h>
#include <hip/hip_bf16.h>

// ---------------------------------------------------------------------------
// HINormer forward (gh path only; the r/re_conv chain is dead w.r.t. outputs).
//
//   gh0[n]   = x[n] @ fcW[type[n]] + fcB[type[n]]
//   deg[c]   = 1 + in_deg(c);  dis = deg^-0.5
//   per layer: xws = (gh @ W)*dis;  gh = relu((xws[c] + sum_in xws[row])*dis + b)
//   out0[b]  = gh[seqs[b,0]] @ predW + predB ;  out1[b] = (float)label[ego]
//
// R3: scatter-atomics (300MB/layer HBM writes, 2x255us) replaced by CSR build
// (once) + fused gather/finalize per layer.
// ---------------------------------------------------------------------------

#define NPB 32

__global__ __launch_bounds__(256) void k_fc(const float* __restrict__ x,
                                            const int* __restrict__ node_type,
                                            const float* __restrict__ fcW,
                                            const float* __restrict__ fcB,
                                            float* __restrict__ gh, int n_nodes) {
  __shared__ float xs[NPB * 128];
  __shared__ float Ws[128 * 128];
  const int t = threadIdx.x;
  const int nbase = blockIdx.x * NPB;
  const int nend = min(nbase + NPB, n_nodes);

  for (int k = 0; k < 16; ++k) {
    int idx = k * 256 + t;
    int node = nbase + (idx >> 7);
    xs[idx] = (node < n_nodes) ? x[(size_t)nbase * 128 + idx] : 0.0f;
  }
  const int t0 = node_type[nbase];
  const int t1 = node_type[nend - 1];
  const bool uniform = (t0 == t1);  // node_type sorted
  if (uniform) {
    const float* W = fcW + (size_t)t0 * 128 * 128;
    for (int k = 0; k < 64; ++k) {
      int idx = k * 256 + t;
      Ws[idx] = W[idx];
    }
  }
  __syncthreads();

  const int dq = (t & 31) * 4;
  const int g = t >> 5;
  if (uniform) {
    float4 bias = *reinterpret_cast<const float4*>(fcB + (size_t)t0 * 128 + dq);
    float4 acc[4];
#pragma unroll
    for (int k = 0; k < 4; ++k) acc[k] = bias;
#pragma unroll 8
    for (int i = 0; i < 128; ++i) {
      float4 w = *reinterpret_cast<const float4*>(&Ws[i * 128 + dq]);
#pragma unroll
      for (int k = 0; k < 4; ++k) {
        float xv = xs[(g + 8 * k) * 128 + i];
        acc[k].x += xv * w.x; acc[k].y += xv * w.y;
        acc[k].z += xv * w.z; acc[k].w += xv * w.w;
      }
    }
#pragma unroll
    for (int k = 0; k < 4; ++k) {
      int node = nbase + g + 8 * k;
      if (node < n_nodes)
        *reinterpret_cast<float4*>(gh + (size_t)node * 128 + dq) = acc[k];
    }
  } else {
    for (int k = 0; k < 4; ++k) {
      int node = nbase + g + 8 * k;
      if (node >= n_nodes) continue;
      int tn = node_type[node];
      const float* W = fcW + (size_t)tn * 128 * 128;
      float4 acc = *reinterpret_cast<const float4*>(fcB + (size_t)tn * 128 + dq);
      for (int i = 0; i < 128; ++i) {
        float4 w = *reinterpret_cast<const float4*>(W + i * 128 + dq);
        float xv = xs[(g + 8 * k) * 128 + i];
        acc.x += xv * w.x; acc.y += xv * w.y;
        acc.z += xv * w.z; acc.w += xv * w.w;
      }
      *reinterpret_cast<float4*>(gh + (size_t)node * 128 + dq) = acc;
    }
  }
}

__global__ __launch_bounds__(256) void k_gemm_scale(const float* __restrict__ hin,
                                                    const float* __restrict__ W,
                                                    const float* __restrict__ dis,
                                                    float* __restrict__ xws,
                                                    int n_nodes) {
  __shared__ float xs[NPB * 128];
  __shared__ float Ws[128 * 128];
  const int t = threadIdx.x;
  const int nbase = blockIdx.x * NPB;

  for (int k = 0; k < 16; ++k) {
    int idx = k * 256 + t;
    int node = nbase + (idx >> 7);
    xs[idx] = (node < n_nodes) ? hin[(size_t)nbase * 128 + idx] : 0.0f;
  }
  for (int k = 0; k < 64; ++k) {
    int idx = k * 256 + t;
    Ws[idx] = W[idx];
  }
  __syncthreads();

  const int dq = (t & 31) * 4;
  const int g = t >> 5;
  float4 acc[4];
#pragma unroll
  for (int k = 0; k < 4; ++k) acc[k] = make_float4(0.f, 0.f, 0.f, 0.f);
#pragma unroll 8
  for (int i = 0; i < 128; ++i) {
    float4 w = *reinterpret_cast<const float4*>(&Ws[i * 128 + dq]);
#pragma unroll
    for (int k = 0; k < 4; ++k) {
      float xv = xs[(g + 8 * k) * 128 + i];
      acc[k].x += xv * w.x; acc[k].y += xv * w.y;
      acc[k].z += xv * w.z; acc[k].w += xv * w.w;
    }
  }
#pragma unroll
  for (int k = 0; k < 4; ++k) {
    int node = nbase + g + 8 * k;
    if (node < n_nodes) {
      float s = dis[node];
      float4 v = make_float4(acc[k].x * s, acc[k].y * s, acc[k].z * s, acc[k].w * s);
      *reinterpret_cast<float4*>(xws + (size_t)node * 128 + dq) = v;
    }
  }
}

// ---- CSR build --------------------------------------------------------------
__global__ void k_zero(int* __restrict__ p, int n) {
  int i = blockIdx.x * 256 + threadIdx.x;
  if (i < n) p[i] = 0;
}

__global__ void k_count(const int* __restrict__ col, int* __restrict__ ecnt, int e) {
  int i = blockIdx.x * 256 + threadIdx.x;
  if (i < e) atomicAdd(&ecnt[col[i]], 1);
}

__global__ __launch_bounds__(256) void k_scan1(const int* __restrict__ ecnt,
                                               int* __restrict__ scanex,
                                               int* __restrict__ partials, int n) {
  __shared__ int s[256];
  const int t = threadIdx.x;
  const int i = blockIdx.x * 256 + t;
  int v = (i < n) ? ecnt[i] : 0;
  s[t] = v;
  __syncthreads();
  for (int off = 1; off < 256; off <<= 1) {
    int add = (t >= off) ? s[t - off] : 0;
    __syncthreads();
    s[t] += add;
    __syncthreads();
  }
  if (i < n) scanex[i] = s[t] - v;
  if (t == 255) partials[blockIdx.x] = s[t];
}

__global__ __launch_bounds__(256) void k_scan2(int* __restrict__ partials, int np) {
  __shared__ int s[256];
  const int t = threadIdx.x;
  int v = (t < np) ? partials[t] : 0;
  s[t] = v;
  __syncthreads();
  for (int off = 1; off < 256; off <<= 1) {
    int add = (t >= off) ? s[t - off] : 0;
    __syncthreads();
    s[t] += add;
    __syncthreads();
  }
  if (t < np) partials[t] = s[t] - v;  // exclusive
}

// col_ptr/cursor finalize + dis in one pass
__global__ void k_scan3(const int* __restrict__ scanex, const int* __restrict__ partials,
                        const int* __restrict__ ecnt, int* __restrict__ col_ptr,
                        int* __restrict__ cursor, float* __restrict__ dis,
                        int n, int e_total) {
  int i = blockIdx.x * 256 + threadIdx.x;
  if (i < n) {
    int p = scanex[i] + partials[blockIdx.x / 1];  // partials indexed by scan1 block
    // NOTE: scan1 block size == this block size == 256, same blocking
    p = scanex[i] + partials[i >> 8];
    col_ptr[i] = p;
    cursor[i] = p;
    dis[i] = rsqrtf((float)(ecnt[i] + 1));
  }
  if (i == 0) col_ptr[n] = e_total;
}

__global__ void k_fill(const int* __restrict__ row, const int* __restrict__ col,
                       int* __restrict__ cursor, int* __restrict__ edge_row, int e) {
  int i = blockIdx.x * 256 + threadIdx.x;
  if (i < e) {
    int c = col[i];
    int pos = atomicAdd(&cursor[c], 1);
    edge_row[pos] = row[i];
  }
}

// ---- fused gather + finalize ------------------------------------------------
__global__ __launch_bounds__(256) void k_gather(const int* __restrict__ col_ptr,
                                                const int* __restrict__ edge_row,
                                                const float* __restrict__ xws,
                                                const float* __restrict__ dis,
                                                const float* __restrict__ bias,
                                                float* __restrict__ gh, int n_nodes) {
  int gid = blockIdx.x * 256 + threadIdx.x;
  int c = gid >> 5;
  if (c >= n_nodes) return;
  int q = (gid & 31) * 4;
  float4 acc = *reinterpret_cast<const float4*>(xws + (size_t)c * 128 + q);  // self
  int e0 = col_ptr[c], e1 = col_ptr[c + 1];
  for (int e = e0; e < e1; ++e) {
    int r = edge_row[e];
    float4 v = *reinterpret_cast<const float4*>(xws + (size_t)r * 128 + q);
    acc.x += v.x; acc.y += v.y; acc.z += v.z; acc.w += v.w;
  }
  float s = dis[c];
  float4 b4 = *reinterpret_cast<const float4*>(bias + q);
  float4 o = make_float4(fmaxf(acc.x * s + b4.x, 0.f), fmaxf(acc.y * s + b4.y, 0.f),
                         fmaxf(acc.z * s + b4.z, 0.f), fmaxf(acc.w * s + b4.w, 0.f));
  *reinterpret_cast<float4*>(gh + (size_t)c * 128 + q) = o;
}

__global__ void k_pred(const float* __restrict__ gh, const int* __restrict__ seqs,
                       const int* __restrict__ label, const float* __restrict__ predW,
                       const float* __restrict__ predB, float* __restrict__ out,
                       float* __restrict__ out_label, int b_total, int n_classes,
                       int slen) {
  int tid = blockIdx.x * 256 + threadIdx.x;
  int b = tid / n_classes;
  if (b >= b_total) return;
  int c = tid - b * n_classes;
  int ego = seqs[(size_t)b * slen];
  const float* g = gh + (size_t)ego * 128;
  float s = predB[c];
#pragma unroll 8
  for (int i = 0; i < 128; ++i) s += g[i] * predW[i * n_classes + c];
  out[(size_t)b * n_classes + c] = s;
  if (c == 0) out_label[b] = (float)label[ego];
}

extern "C" void kernel_launch(void* const* d_in, const int* in_sizes, int n_in,
                              void* d_out, int out_size, void* d_ws, size_t ws_size,
                              hipStream_t stream) {
  const float* x     = (const float*)d_in[0];
  const int*   label = (const int*)d_in[1];
  const int*   seqs  = (const int*)d_in[2];
  const int*   edge  = (const int*)d_in[3];
  const int*   ntype = (const int*)d_in[4];
  const float* fcW   = (const float*)d_in[5];
  const float* fcB   = (const float*)d_in[6];
  const float* gcnW  = (const float*)d_in[7];
  const float* gcnB  = (const float*)d_in[8];
  const float* predW = (const float*)d_in[12];
  const float* predB = (const float*)d_in[13];

  const int n = in_sizes[0] / 128;        // 50000
  const int e = in_sizes[3] / 2;          // 600000
  const int L = in_sizes[8] / 128;        // 2
  const int C = in_sizes[13];             // 16
  const int slen = 16;
  const int b_total = in_sizes[2] / slen; // 2048

  const int* row = edge;
  const int* col = edge + e;

  char* ws = (char*)d_ws;
  const size_t node_mat = (size_t)n * 128 * sizeof(float);
  float* gh      = (float*)ws;                              ws += node_mat;
  float* xws     = (float*)ws;                              ws += node_mat;
  float* dis     = (float*)ws;                              ws += (size_t)n * 4;
  int*   ecnt    = (int*)ws;                                ws += (size_t)n * 4;
  int*   scanex  = (int*)ws;                                ws += (size_t)n * 4;
  int*   col_ptr = (int*)ws;                                ws += (size_t)(n + 16) * 4;
  int*   cursor  = (int*)ws;                                ws += (size_t)n * 4;
  int*   partial = (int*)ws;                                ws += 256 * 4;
  int*   edge_row= (int*)ws;                                ws += (size_t)e * 4;

  float* out_logits = (float*)d_out;
  float* out_label  = out_logits + (size_t)b_total * C;

  const int nb = (n + NPB - 1) / NPB;
  const int nscan = (n + 255) / 256;  // 196 <= 256

  // node features (independent of CSR build -> back-to-back launches overlap)
  hipLaunchKernelGGL(k_fc, dim3(nb), dim3(256), 0, stream, x, ntype, fcW, fcB, gh, n);

  // CSR build (once)
  hipLaunchKernelGGL(k_zero, dim3(nscan), dim3(256), 0, stream, ecnt, n);
  hipLaunchKernelGGL(k_count, dim3((e + 255) / 256), dim3(256), 0, stream, col, ecnt, e);
  hipLaunchKernelGGL(k_scan1, dim3(nscan), dim3(256), 0, stream, ecnt, scanex, partial, n);
  hipLaunchKernelGGL(k_scan2, dim3(1), dim3(256), 0, stream, partial, nscan);
  hipLaunchKernelGGL(k_scan3, dim3(nscan), dim3(256), 0, stream, scanex, partial, ecnt,
                     col_ptr, cursor, dis, n, e);
  hipLaunchKernelGGL(k_fill, dim3((e + 255) / 256), dim3(256), 0, stream, row, col,
                     cursor, edge_row, e);

  for (int l = 0; l < L; ++l) {
    hipLaunchKernelGGL(k_gemm_scale, dim3(nb), dim3(256), 0, stream,
                       gh, gcnW + (size_t)l * 128 * 128, dis, xws, n);
    hipLaunchKernelGGL(k_gather, dim3((n * 32 + 255) / 256), dim3(256), 0, stream,
                       col_ptr, edge_row, xws, dis, gcnB + (size_t)l * 128, gh, n);
  }
  hipLaunchKernelGGL(k_pred, dim3((b_total * C + 255) / 256), dim3(256), 0, stream,
                     gh, seqs, label, predW, predB, out_logits, out_label,
                     b_total, C, slen);
}

// Round 4
// 379.492 us; speedup vs baseline: 2.0886x; 1.0295x over previous
//
#include <hip/hip_runtime.h>
#include <hip/hip_bf16.h>

// ---------------------------------------------------------------------------
// HINormer forward, bf16+MFMA backbone (R4).
//   gh0 = x @ fcW[type] + fcB[type]          (MFMA, bf16 in / f32 acc)
//   dis = (1+in_deg)^-0.5
//   per layer: xws = (gh @ W)*dis (MFMA);  gh = relu((xws[c]+sum xws[row])*dis+b)
//   out0 = gh[ego] @ predW + predB ; out1 = (float)label[ego]
// gh/xws stored as bf16 (halves gather HBM traffic); weights pre-transposed
// to bf16 Wt[dout][k] once. LDS tiles XOR-swizzled (T2) for ds_read_b128.
// ---------------------------------------------------------------------------

typedef __attribute__((ext_vector_type(8))) short short8;   // 8 bf16
typedef __attribute__((ext_vector_type(4))) float f32x4;
typedef unsigned short u16;

__device__ __forceinline__ float bf2f(u16 u) {
  union { float f; unsigned int i; } v; v.i = (unsigned int)u << 16; return v.f;
}
__device__ __forceinline__ u16 f2bf(float f) {
  union { float f; unsigned int i; } v; v.f = f;
  return (u16)((v.i + 0x7FFF + ((v.i >> 16) & 1)) >> 16);
}

#define NPB 64  // nodes per GEMM block

// ---- weight pre-transpose: wt[m][d][k] = W[m][k][d] as bf16 ----------------
__global__ void k_wt(const float* __restrict__ fcW, const float* __restrict__ gcnW,
                     u16* __restrict__ wt, int T, int total) {
  int i = blockIdx.x * 256 + threadIdx.x;
  if (i >= total) return;
  int m = i >> 14;
  int dk = i & 16383;
  int d = dk >> 7, k = dk & 127;
  const float* src = (m < T) ? (fcW + ((size_t)m << 14)) : (gcnW + ((size_t)(m - T) << 14));
  wt[i] = f2bf(src[k * 128 + d]);
}

// ---- shared MFMA tile core --------------------------------------------------
// smem: xs = 64x128 bf16 swizzled (16KB) at 0 ; wt = 128x128 bf16 swizzled (32KB)
#define SWZ(row, byte) ((byte) ^ (((row) & 7) << 4))

__device__ __forceinline__ void stage_wt(char* smem_wt, const u16* __restrict__ wtg,
                                         int t) {
  int row = t >> 1;
  int h = (t & 1) * 64;
  const u16* src = wtg + row * 128 + h;
#pragma unroll
  for (int j = 0; j < 8; ++j) {
    short8 v = *(const short8*)(src + j * 8);
    int byte = row * 256 + (h + j * 8) * 2;
    *(short8*)(smem_wt + SWZ(row, byte)) = v;
  }
}

__device__ __forceinline__ void mfma_core(const char* smem_xs, const char* smem_wt,
                                          int t, f32x4 acc[4][2]) {
  const int lane = t & 63, w = t >> 6;
  const int lr = lane & 15, lk = lane >> 4;
#pragma unroll
  for (int ks = 0; ks < 4; ++ks) {
    const int kb = ks * 64 + lk * 16;  // byte offset into k (8 bf16 = 16B)
    short8 a[4], b[2];
#pragma unroll
    for (int rg = 0; rg < 4; ++rg) {
      int row = rg * 16 + lr;
      a[rg] = *(const short8*)(smem_xs + SWZ(row, row * 256 + kb));
    }
#pragma unroll
    for (int ch = 0; ch < 2; ++ch) {
      int row = w * 32 + ch * 16 + lr;
      b[ch] = *(const short8*)(smem_wt + SWZ(row, row * 256 + kb));
    }
#pragma unroll
    for (int rg = 0; rg < 4; ++rg)
#pragma unroll
      for (int ch = 0; ch < 2; ++ch)
        acc[rg][ch] = __builtin_amdgcn_mfma_f32_16x16x32_bf16(a[rg], b[ch], acc[rg][ch], 0, 0, 0);
  }
}

// ---- k_fc: x(f32) @ fcW[type] + fcB ; out gh bf16 --------------------------
__global__ __launch_bounds__(256) void k_fc(const float* __restrict__ x,
                                            const int* __restrict__ node_type,
                                            const u16* __restrict__ wt_fc,  // [T][128][128]
                                            const float* __restrict__ fcW,  // f32 fallback
                                            const float* __restrict__ fcB,
                                            u16* __restrict__ gh, int n_nodes) {
  __shared__ char smem[49152];
  char* smem_xs = smem;
  char* smem_wt = smem + 16384;
  const int t = threadIdx.x;
  const int nbase = blockIdx.x * NPB;
  const int nend = min(nbase + NPB, n_nodes);
  const int t0 = node_type[nbase];
  const bool uniform = (t0 == node_type[nend - 1]);  // sorted types

  if (uniform) {
    // stage x tile -> bf16 swizzled LDS
    {
      int row = t >> 2;
      int c0 = (t & 3) * 32;
      int node = nbase + row;
      float xv[32];
      if (node < n_nodes) {
        const float4* src = (const float4*)(x + (size_t)node * 128 + c0);
#pragma unroll
        for (int j = 0; j < 8; ++j) ((float4*)xv)[j] = src[j];
      } else {
#pragma unroll
        for (int j = 0; j < 32; ++j) xv[j] = 0.0f;
      }
#pragma unroll
      for (int j = 0; j < 4; ++j) {
        u16 tmp[8];
#pragma unroll
        for (int q = 0; q < 8; ++q) tmp[q] = f2bf(xv[j * 8 + q]);
        int byte = row * 256 + (c0 + j * 8) * 2;
        *(short8*)(smem_xs + SWZ(row, byte)) = *(short8*)tmp;
      }
    }
    stage_wt(smem_wt, wt_fc + ((size_t)t0 << 14), t);
    __syncthreads();

    f32x4 acc[4][2];
#pragma unroll
    for (int rg = 0; rg < 4; ++rg)
#pragma unroll
      for (int ch = 0; ch < 2; ++ch) acc[rg][ch] = (f32x4){0.f, 0.f, 0.f, 0.f};
    mfma_core(smem_xs, smem_wt, t, acc);

    const int lane = t & 63, w = t >> 6;
    const int lr = lane & 15, lk = lane >> 4;
#pragma unroll
    for (int rg = 0; rg < 4; ++rg) {
#pragma unroll
      for (int ch = 0; ch < 2; ++ch) {
        int dout = w * 32 + ch * 16 + lr;
        float bv = fcB[t0 * 128 + dout];
#pragma unroll
        for (int reg = 0; reg < 4; ++reg) {
          int node = nbase + rg * 16 + lk * 4 + reg;
          if (node < n_nodes)
            gh[(size_t)node * 128 + dout] = f2bf(acc[rg][ch][reg] + bv);
        }
      }
    }
  } else {
    // type boundary inside tile: <= T-1 blocks total, scalar f32 path
    int d = t & 127;
    for (int node = nbase + (t >> 7); node < nend; node += 2) {
      int tn = node_type[node];
      const float* W = fcW + ((size_t)tn << 14);
      float acc = fcB[tn * 128 + d];
      const float* xr = x + (size_t)node * 128;
#pragma unroll 8
      for (int k = 0; k < 128; ++k) acc += xr[k] * W[k * 128 + d];
      gh[(size_t)node * 128 + d] = f2bf(acc);
    }
  }
}

// ---- k_gemm_scale: xws = (gh @ W) * dis ; bf16 in/out ----------------------
__global__ __launch_bounds__(256) void k_gemm_scale(const u16* __restrict__ ghin,
                                                    const u16* __restrict__ wtg,  // [128][128]
                                                    const float* __restrict__ dis,
                                                    u16* __restrict__ xws, int n_nodes) {
  __shared__ char smem[49152];
  char* smem_xs = smem;
  char* smem_wt = smem + 16384;
  const int t = threadIdx.x;
  const int nbase = blockIdx.x * NPB;

  {
    int row = t >> 2;
    int c0 = (t & 3) * 32;
    int node = nbase + row;
    if (node < n_nodes) {
      const u16* src = ghin + (size_t)node * 128 + c0;
#pragma unroll
      for (int j = 0; j < 4; ++j) {
        short8 v = *(const short8*)(src + j * 8);
        int byte = row * 256 + (c0 + j * 8) * 2;
        *(short8*)(smem_xs + SWZ(row, byte)) = v;
      }
    } else {
      short8 z = (short8){0, 0, 0, 0, 0, 0, 0, 0};
#pragma unroll
      for (int j = 0; j < 4; ++j) {
        int byte = row * 256 + (c0 + j * 8) * 2;
        *(short8*)(smem_xs + SWZ(row, byte)) = z;
      }
    }
  }
  stage_wt(smem_wt, wtg, t);
  __syncthreads();

  f32x4 acc[4][2];
#pragma unroll
  for (int rg = 0; rg < 4; ++rg)
#pragma unroll
    for (int ch = 0; ch < 2; ++ch) acc[rg][ch] = (f32x4){0.f, 0.f, 0.f, 0.f};
  mfma_core(smem_xs, smem_wt, t, acc);

  const int lane = t & 63, w = t >> 6;
  const int lr = lane & 15, lk = lane >> 4;
#pragma unroll
  for (int rg = 0; rg < 4; ++rg) {
#pragma unroll
    for (int reg = 0; reg < 4; ++reg) {
      int node = nbase + rg * 16 + lk * 4 + reg;
      if (node < n_nodes) {
        float s = dis[node];
#pragma unroll
        for (int ch = 0; ch < 2; ++ch) {
          int dout = w * 32 + ch * 16 + lr;
          xws[(size_t)node * 128 + dout] = f2bf(acc[rg][ch][reg] * s);
        }
      }
    }
  }
}

// ---- CSR build --------------------------------------------------------------
__global__ void k_zero(int* __restrict__ p, int n) {
  int i = blockIdx.x * 256 + threadIdx.x;
  if (i < n) p[i] = 0;
}

__global__ void k_count(const int* __restrict__ col, int* __restrict__ ecnt, int e) {
  int i = blockIdx.x * 256 + threadIdx.x;
  if (i < e) atomicAdd(&ecnt[col[i]], 1);
}

__global__ __launch_bounds__(256) void k_scan1(const int* __restrict__ ecnt,
                                               int* __restrict__ scanex,
                                               int* __restrict__ partials, int n) {
  __shared__ int s[256];
  const int t = threadIdx.x;
  const int i = blockIdx.x * 256 + t;
  int v = (i < n) ? ecnt[i] : 0;
  s[t] = v;
  __syncthreads();
  for (int off = 1; off < 256; off <<= 1) {
    int add = (t >= off) ? s[t - off] : 0;
    __syncthreads();
    s[t] += add;
    __syncthreads();
  }
  if (i < n) scanex[i] = s[t] - v;
  if (t == 255) partials[blockIdx.x] = s[t];
}

__global__ __launch_bounds__(256) void k_scan2(int* __restrict__ partials, int np) {
  __shared__ int s[256];
  const int t = threadIdx.x;
  int v = (t < np) ? partials[t] : 0;
  s[t] = v;
  __syncthreads();
  for (int off = 1; off < 256; off <<= 1) {
    int add = (t >= off) ? s[t - off] : 0;
    __syncthreads();
    s[t] += add;
    __syncthreads();
  }
  if (t < np) partials[t] = s[t] - v;  // exclusive
}

__global__ void k_scan3(const int* __restrict__ scanex, const int* __restrict__ partials,
                        const int* __restrict__ ecnt, int* __restrict__ col_ptr,
                        int* __restrict__ cursor, float* __restrict__ dis,
                        int n, int e_total) {
  int i = blockIdx.x * 256 + threadIdx.x;
  if (i < n) {
    int p = scanex[i] + partials[i >> 8];
    col_ptr[i] = p;
    cursor[i] = p;
    dis[i] = rsqrtf((float)(ecnt[i] + 1));
  }
  if (i == 0) col_ptr[n] = e_total;
}

__global__ void k_fill(const int* __restrict__ row, const int* __restrict__ col,
                       int* __restrict__ cursor, int* __restrict__ edge_row, int e) {
  int i = blockIdx.x * 256 + threadIdx.x;
  if (i < e) {
    int c = col[i];
    int pos = atomicAdd(&cursor[c], 1);
    edge_row[pos] = row[i];
  }
}

// ---- fused gather + finalize: 1 wave/node, 4 edges in flight ---------------
__global__ __launch_bounds__(256) void k_gather(const int* __restrict__ col_ptr,
                                                const int* __restrict__ edge_row,
                                                const u16* __restrict__ xws,
                                                const float* __restrict__ dis,
                                                const float* __restrict__ bias,
                                                u16* __restrict__ gh, int n_nodes) {
  const int t = threadIdx.x;
  const int node = blockIdx.x * 4 + (t >> 6);
  if (node >= n_nodes) return;
  const int lane = t & 63;
  const int g = lane & 15;   // elem group: elems g*8 .. g*8+7
  const int s = lane >> 4;   // edge slot 0..3
  float acc[8] = {0.f, 0.f, 0.f, 0.f, 0.f, 0.f, 0.f, 0.f};
  if (s == 0) {  // self loop term
    short8 v = *(const short8*)(xws + (size_t)node * 128 + g * 8);
#pragma unroll
    for (int j = 0; j < 8; ++j) acc[j] = bf2f((u16)v[j]);
  }
  const int e0 = col_ptr[node], e1 = col_ptr[node + 1];
  for (int e = e0 + s; e < e1; e += 4) {
    int r = edge_row[e];
    short8 v = *(const short8*)(xws + (size_t)r * 128 + g * 8);
#pragma unroll
    for (int j = 0; j < 8; ++j) acc[j] += bf2f((u16)v[j]);
  }
#pragma unroll
  for (int j = 0; j < 8; ++j) {
    acc[j] += __shfl_xor(acc[j], 16);
    acc[j] += __shfl_xor(acc[j], 32);
  }
  if (s == 0) {
    float ds = dis[node];
    u16 o[8];
#pragma unroll
    for (int j = 0; j < 8; ++j)
      o[j] = f2bf(fmaxf(acc[j] * ds + bias[g * 8 + j], 0.f));
    *(short8*)(gh + (size_t)node * 128 + g * 8) = *(short8*)o;
  }
}

__global__ void k_pred(const u16* __restrict__ gh, const int* __restrict__ seqs,
                       const int* __restrict__ label, const float* __restrict__ predW,
                       const float* __restrict__ predB, float* __restrict__ out,
                       float* __restrict__ out_label, int b_total, int n_classes,
                       int slen) {
  int tid = blockIdx.x * 256 + threadIdx.x;
  int b = tid / n_classes;
  if (b >= b_total) return;
  int c = tid - b * n_classes;
  int ego = seqs[(size_t)b * slen];
  const u16* g = gh + (size_t)ego * 128;
  float s = predB[c];
#pragma unroll 8
  for (int i = 0; i < 128; ++i) s += bf2f(g[i]) * predW[i * n_classes + c];
  out[(size_t)b * n_classes + c] = s;
  if (c == 0) out_label[b] = (float)label[ego];
}

extern "C" void kernel_launch(void* const* d_in, const int* in_sizes, int n_in,
                              void* d_out, int out_size, void* d_ws, size_t ws_size,
                              hipStream_t stream) {
  const float* x     = (const float*)d_in[0];
  const int*   label = (const int*)d_in[1];
  const int*   seqs  = (const int*)d_in[2];
  const int*   edge  = (const int*)d_in[3];
  const int*   ntype = (const int*)d_in[4];
  const float* fcW   = (const float*)d_in[5];
  const float* fcB   = (const float*)d_in[6];
  const float* gcnW  = (const float*)d_in[7];
  const float* gcnB  = (const float*)d_in[8];
  const float* predW = (const float*)d_in[12];
  const float* predB = (const float*)d_in[13];

  const int n = in_sizes[0] / 128;          // 50000
  const int e = in_sizes[3] / 2;            // 600000
  const int T = in_sizes[5] / (128 * 128);  // 4
  const int L = in_sizes[8] / 128;          // 2
  const int C = in_sizes[13];               // 16
  const int slen = 16;
  const int b_total = in_sizes[2] / slen;   // 2048

  const int* row = edge;
  const int* col = edge + e;

  char* ws = (char*)d_ws;
  const size_t node_bf = (size_t)n * 128 * sizeof(u16);
  u16*   gh      = (u16*)ws;                 ws += node_bf;
  u16*   xws     = (u16*)ws;                 ws += node_bf;
  u16*   wt      = (u16*)ws;                 ws += (size_t)(T + L) * 16384 * 2;
  float* dis     = (float*)ws;               ws += (size_t)n * 4;
  int*   ecnt    = (int*)ws;                 ws += (size_t)n * 4;
  int*   scanex  = (int*)ws;                 ws += (size_t)n * 4;
  int*   col_ptr = (int*)ws;                 ws += (size_t)(n + 16) * 4;
  int*   cursor  = (int*)ws;                 ws += (size_t)n * 4;
  int*   partial = (int*)ws;                 ws += 1024 * 4;
  int*   edge_row= (int*)ws;                 ws += (size_t)e * 4;

  float* out_logits = (float*)d_out;
  float* out_label  = out_logits + (size_t)b_total * C;

  const int nb = (n + NPB - 1) / NPB;
  const int nscan = (n + 255) / 256;
  const int wt_total = (T + L) * 16384;

  // weight transpose+cast (once), then node features
  hipLaunchKernelGGL(k_wt, dim3((wt_total + 255) / 256), dim3(256), 0, stream,
                     fcW, gcnW, wt, T, wt_total);
  hipLaunchKernelGGL(k_fc, dim3(nb), dim3(256), 0, stream, x, ntype, wt, fcW, fcB, gh, n);

  // CSR build (once)
  hipLaunchKernelGGL(k_zero, dim3(nscan), dim3(256), 0, stream, ecnt, n);
  hipLaunchKernelGGL(k_count, dim3((e + 255) / 256), dim3(256), 0, stream, col, ecnt, e);
  hipLaunchKernelGGL(k_scan1, dim3(nscan), dim3(256), 0, stream, ecnt, scanex, partial, n);
  hipLaunchKernelGGL(k_scan2, dim3(1), dim3(256), 0, stream, partial, nscan);
  hipLaunchKernelGGL(k_scan3, dim3(nscan), dim3(256), 0, stream, scanex, partial, ecnt,
                     col_ptr, cursor, dis, n, e);
  hipLaunchKernelGGL(k_fill, dim3((e + 255) / 256), dim3(256), 0, stream, row, col,
                     cursor, edge_row, e);

  for (int l = 0; l < L; ++l) {
    hipLaunchKernelGGL(k_gemm_scale, dim3(nb), dim3(256), 0, stream,
                       gh, wt + (size_t)(T + l) * 16384, dis, xws, n);
    hipLaunchKernelGGL(k_gather, dim3((n + 3) / 4), dim3(256), 0, stream,
                       col_ptr, edge_row, xws, dis, gcnB + (size_t)l * 128, gh, n);
  }
  hipLaunchKernelGGL(k_pred, dim3((b_total * C + 255) / 256), dim3(256), 0, stream,
                     gh, seqs, label, predW, predB, out_logits, out_label,
                     b_total, C, slen);
}

// Round 5
// 283.099 us; speedup vs baseline: 2.7997x; 1.3405x over previous
//
#include <hip/hip_runtime.h>
#include <hip/hip_bf16.h>

// ---------------------------------------------------------------------------
// HINormer forward, bf16+MFMA backbone (R5).
//   gh0 = x @ fcW[type] + fcB[type]          (MFMA, bf16 in / f32 acc)
//   dis = (1+in_deg)^-0.5
//   per layer: xws = (gh @ W)*dis (MFMA);  gh = relu((xws[c]+sum xws[row])*dis+b)
//   out0 = gh[ego] @ predW + predB ; out1 = (float)label[ego]
// R5 changes vs R4:
//  - k_fc type-boundary tiles: loop over types with MFMA + masked writeback
//    (kills the 147us scalar straggler tail; <=3 blocks do 2x tile work).
//  - SWZ widened to (row&15)<<4: fragment ds_read_b128 4-way instead of 8-way.
// ---------------------------------------------------------------------------

typedef __attribute__((ext_vector_type(8))) short short8;   // 8 bf16
typedef __attribute__((ext_vector_type(4))) float f32x4;
typedef unsigned short u16;

__device__ __forceinline__ float bf2f(u16 u) {
  union { float f; unsigned int i; } v; v.i = (unsigned int)u << 16; return v.f;
}
__device__ __forceinline__ u16 f2bf(float f) {
  union { float f; unsigned int i; } v; v.f = f;
  return (u16)((v.i + 0x7FFF + ((v.i >> 16) & 1)) >> 16);
}

#define NPB 64  // nodes per GEMM block

// ---- weight pre-transpose: wt[m][d][k] = W[m][k][d] as bf16 ----------------
__global__ void k_wt(const float* __restrict__ fcW, const float* __restrict__ gcnW,
                     u16* __restrict__ wt, int T, int total) {
  int i = blockIdx.x * 256 + threadIdx.x;
  if (i >= total) return;
  int m = i >> 14;
  int dk = i & 16383;
  int d = dk >> 7, k = dk & 127;
  const float* src = (m < T) ? (fcW + ((size_t)m << 14)) : (gcnW + ((size_t)(m - T) << 14));
  wt[i] = f2bf(src[k * 128 + d]);
}

// ---- shared MFMA tile core --------------------------------------------------
// smem: xs = 64x128 bf16 swizzled (16KB) ; wt = 128x128 bf16 swizzled (32KB)
#define SWZ(row, byte) ((byte) ^ (((row) & 15) << 4))

__device__ __forceinline__ void stage_wt(char* smem_wt, const u16* __restrict__ wtg,
                                         int t) {
  int row = t >> 1;
  int h = (t & 1) * 64;
  const u16* src = wtg + row * 128 + h;
#pragma unroll
  for (int j = 0; j < 8; ++j) {
    short8 v = *(const short8*)(src + j * 8);
    int byte = row * 256 + (h + j * 8) * 2;
    *(short8*)(smem_wt + SWZ(row, byte)) = v;
  }
}

__device__ __forceinline__ void mfma_core(const char* smem_xs, const char* smem_wt,
                                          int t, f32x4 acc[4][2]) {
  const int lane = t & 63, w = t >> 6;
  const int lr = lane & 15, lk = lane >> 4;
#pragma unroll
  for (int ks = 0; ks < 4; ++ks) {
    const int kb = ks * 64 + lk * 16;  // byte offset into k (8 bf16 = 16B)
    short8 a[4], b[2];
#pragma unroll
    for (int rg = 0; rg < 4; ++rg) {
      int row = rg * 16 + lr;
      a[rg] = *(const short8*)(smem_xs + SWZ(row, row * 256 + kb));
    }
#pragma unroll
    for (int ch = 0; ch < 2; ++ch) {
      int row = w * 32 + ch * 16 + lr;
      b[ch] = *(const short8*)(smem_wt + SWZ(row, row * 256 + kb));
    }
#pragma unroll
    for (int rg = 0; rg < 4; ++rg)
#pragma unroll
      for (int ch = 0; ch < 2; ++ch)
        acc[rg][ch] = __builtin_amdgcn_mfma_f32_16x16x32_bf16(a[rg], b[ch], acc[rg][ch], 0, 0, 0);
  }
}

// ---- k_fc: x(f32) @ fcW[type] + fcB ; out gh bf16 --------------------------
// Mixed-type tiles (<=3 of 782): loop over the tile's type range, full MFMA
// each, masked writeback. No scalar fallback.
__global__ __launch_bounds__(256) void k_fc(const float* __restrict__ x,
                                            const int* __restrict__ node_type,
                                            const u16* __restrict__ wt_fc,  // [T][128][128]
                                            const float* __restrict__ fcB,
                                            u16* __restrict__ gh, int n_nodes) {
  __shared__ char smem[49152];
  char* smem_xs = smem;
  char* smem_wt = smem + 16384;
  const int t = threadIdx.x;
  const int nbase = blockIdx.x * NPB;
  const int nend = min(nbase + NPB, n_nodes);
  const int t0 = node_type[nbase];
  const int t1 = node_type[nend - 1];   // sorted types -> tile covers [t0,t1]

  // stage x tile -> bf16 swizzled LDS
  {
    int row = t >> 2;
    int c0 = (t & 3) * 32;
    int node = nbase + row;
    float xv[32];
    if (node < n_nodes) {
      const float4* src = (const float4*)(x + (size_t)node * 128 + c0);
#pragma unroll
      for (int j = 0; j < 8; ++j) ((float4*)xv)[j] = src[j];
    } else {
#pragma unroll
      for (int j = 0; j < 32; ++j) xv[j] = 0.0f;
    }
#pragma unroll
    for (int j = 0; j < 4; ++j) {
      u16 tmp[8];
#pragma unroll
      for (int q = 0; q < 8; ++q) tmp[q] = f2bf(xv[j * 8 + q]);
      int byte = row * 256 + (c0 + j * 8) * 2;
      *(short8*)(smem_xs + SWZ(row, byte)) = *(short8*)tmp;
    }
  }

  const int lane = t & 63, w = t >> 6;
  const int lr = lane & 15, lk = lane >> 4;

  for (int tt = t0; tt <= t1; ++tt) {
    if (tt > t0) __syncthreads();  // drain prior-iteration smem_wt reads
    stage_wt(smem_wt, wt_fc + ((size_t)tt << 14), t);
    __syncthreads();

    f32x4 acc[4][2];
#pragma unroll
    for (int rg = 0; rg < 4; ++rg)
#pragma unroll
      for (int ch = 0; ch < 2; ++ch) acc[rg][ch] = (f32x4){0.f, 0.f, 0.f, 0.f};
    mfma_core(smem_xs, smem_wt, t, acc);

#pragma unroll
    for (int rg = 0; rg < 4; ++rg) {
#pragma unroll
      for (int reg = 0; reg < 4; ++reg) {
        int node = nbase + rg * 16 + lk * 4 + reg;
        if (node < n_nodes && node_type[node] == tt) {
#pragma unroll
          for (int ch = 0; ch < 2; ++ch) {
            int dout = w * 32 + ch * 16 + lr;
            gh[(size_t)node * 128 + dout] = f2bf(acc[rg][ch][reg] + fcB[tt * 128 + dout]);
          }
        }
      }
    }
  }
}

// ---- k_gemm_scale: xws = (gh @ W) * dis ; bf16 in/out ----------------------
__global__ __launch_bounds__(256) void k_gemm_scale(const u16* __restrict__ ghin,
                                                    const u16* __restrict__ wtg,  // [128][128]
                                                    const float* __restrict__ dis,
                                                    u16* __restrict__ xws, int n_nodes) {
  __shared__ char smem[49152];
  char* smem_xs = smem;
  char* smem_wt = smem + 16384;
  const int t = threadIdx.x;
  const int nbase = blockIdx.x * NPB;

  {
    int row = t >> 2;
    int c0 = (t & 3) * 32;
    int node = nbase + row;
    if (node < n_nodes) {
      const u16* src = ghin + (size_t)node * 128 + c0;
#pragma unroll
      for (int j = 0; j < 4; ++j) {
        short8 v = *(const short8*)(src + j * 8);
        int byte = row * 256 + (c0 + j * 8) * 2;
        *(short8*)(smem_xs + SWZ(row, byte)) = v;
      }
    } else {
      short8 z = (short8){0, 0, 0, 0, 0, 0, 0, 0};
#pragma unroll
      for (int j = 0; j < 4; ++j) {
        int byte = row * 256 + (c0 + j * 8) * 2;
        *(short8*)(smem_xs + SWZ(row, byte)) = z;
      }
    }
  }
  stage_wt(smem_wt, wtg, t);
  __syncthreads();

  f32x4 acc[4][2];
#pragma unroll
  for (int rg = 0; rg < 4; ++rg)
#pragma unroll
    for (int ch = 0; ch < 2; ++ch) acc[rg][ch] = (f32x4){0.f, 0.f, 0.f, 0.f};
  mfma_core(smem_xs, smem_wt, t, acc);

  const int lane = t & 63, w = t >> 6;
  const int lr = lane & 15, lk = lane >> 4;
#pragma unroll
  for (int rg = 0; rg < 4; ++rg) {
#pragma unroll
    for (int reg = 0; reg < 4; ++reg) {
      int node = nbase + rg * 16 + lk * 4 + reg;
      if (node < n_nodes) {
        float s = dis[node];
#pragma unroll
        for (int ch = 0; ch < 2; ++ch) {
          int dout = w * 32 + ch * 16 + lr;
          xws[(size_t)node * 128 + dout] = f2bf(acc[rg][ch][reg] * s);
        }
      }
    }
  }
}

// ---- CSR build --------------------------------------------------------------
__global__ void k_zero(int* __restrict__ p, int n) {
  int i = blockIdx.x * 256 + threadIdx.x;
  if (i < n) p[i] = 0;
}

__global__ void k_count(const int* __restrict__ col, int* __restrict__ ecnt, int e) {
  int i = blockIdx.x * 256 + threadIdx.x;
  if (i < e) atomicAdd(&ecnt[col[i]], 1);
}

__global__ __launch_bounds__(256) void k_scan1(const int* __restrict__ ecnt,
                                               int* __restrict__ scanex,
                                               int* __restrict__ partials, int n) {
  __shared__ int s[256];
  const int t = threadIdx.x;
  const int i = blockIdx.x * 256 + t;
  int v = (i < n) ? ecnt[i] : 0;
  s[t] = v;
  __syncthreads();
  for (int off = 1; off < 256; off <<= 1) {
    int add = (t >= off) ? s[t - off] : 0;
    __syncthreads();
    s[t] += add;
    __syncthreads();
  }
  if (i < n) scanex[i] = s[t] - v;
  if (t == 255) partials[blockIdx.x] = s[t];
}

__global__ __launch_bounds__(256) void k_scan2(int* __restrict__ partials, int np) {
  __shared__ int s[256];
  const int t = threadIdx.x;
  int v = (t < np) ? partials[t] : 0;
  s[t] = v;
  __syncthreads();
  for (int off = 1; off < 256; off <<= 1) {
    int add = (t >= off) ? s[t - off] : 0;
    __syncthreads();
    s[t] += add;
    __syncthreads();
  }
  if (t < np) partials[t] = s[t] - v;  // exclusive
}

__global__ void k_scan3(const int* __restrict__ scanex, const int* __restrict__ partials,
                        const int* __restrict__ ecnt, int* __restrict__ col_ptr,
                        int* __restrict__ cursor, float* __restrict__ dis,
                        int n, int e_total) {
  int i = blockIdx.x * 256 + threadIdx.x;
  if (i < n) {
    int p = scanex[i] + partials[i >> 8];
    col_ptr[i] = p;
    cursor[i] = p;
    dis[i] = rsqrtf((float)(ecnt[i] + 1));
  }
  if (i == 0) col_ptr[n] = e_total;
}

__global__ void k_fill(const int* __restrict__ row, const int* __restrict__ col,
                       int* __restrict__ cursor, int* __restrict__ edge_row, int e) {
  int i = blockIdx.x * 256 + threadIdx.x;
  if (i < e) {
    int c = col[i];
    int pos = atomicAdd(&cursor[c], 1);
    edge_row[pos] = row[i];
  }
}

// ---- fused gather + finalize: 1 wave/node, 4 edges in flight ---------------
__global__ __launch_bounds__(256) void k_gather(const int* __restrict__ col_ptr,
                                                const int* __restrict__ edge_row,
                                                const u16* __restrict__ xws,
                                                const float* __restrict__ dis,
                                                const float* __restrict__ bias,
                                                u16* __restrict__ gh, int n_nodes) {
  const int t = threadIdx.x;
  const int node = blockIdx.x * 4 + (t >> 6);
  if (node >= n_nodes) return;
  const int lane = t & 63;
  const int g = lane & 15;   // elem group: elems g*8 .. g*8+7
  const int s = lane >> 4;   // edge slot 0..3
  float acc[8] = {0.f, 0.f, 0.f, 0.f, 0.f, 0.f, 0.f, 0.f};
  if (s == 0) {  // self loop term
    short8 v = *(const short8*)(xws + (size_t)node * 128 + g * 8);
#pragma unroll
    for (int j = 0; j < 8; ++j) acc[j] = bf2f((u16)v[j]);
  }
  const int e0 = col_ptr[node], e1 = col_ptr[node + 1];
  for (int e = e0 + s; e < e1; e += 4) {
    int r = edge_row[e];
    short8 v = *(const short8*)(xws + (size_t)r * 128 + g * 8);
#pragma unroll
    for (int j = 0; j < 8; ++j) acc[j] += bf2f((u16)v[j]);
  }
#pragma unroll
  for (int j = 0; j < 8; ++j) {
    acc[j] += __shfl_xor(acc[j], 16);
    acc[j] += __shfl_xor(acc[j], 32);
  }
  if (s == 0) {
    float ds = dis[node];
    u16 o[8];
#pragma unroll
    for (int j = 0; j < 8; ++j)
      o[j] = f2bf(fmaxf(acc[j] * ds + bias[g * 8 + j], 0.f));
    *(short8*)(gh + (size_t)node * 128 + g * 8) = *(short8*)o;
  }
}

__global__ void k_pred(const u16* __restrict__ gh, const int* __restrict__ seqs,
                       const int* __restrict__ label, const float* __restrict__ predW,
                       const float* __restrict__ predB, float* __restrict__ out,
                       float* __restrict__ out_label, int b_total, int n_classes,
                       int slen) {
  int tid = blockIdx.x * 256 + threadIdx.x;
  int b = tid / n_classes;
  if (b >= b_total) return;
  int c = tid - b * n_classes;
  int ego = seqs[(size_t)b * slen];
  const u16* g = gh + (size_t)ego * 128;
  float s = predB[c];
#pragma unroll 8
  for (int i = 0; i < 128; ++i) s += bf2f(g[i]) * predW[i * n_classes + c];
  out[(size_t)b * n_classes + c] = s;
  if (c == 0) out_label[b] = (float)label[ego];
}

extern "C" void kernel_launch(void* const* d_in, const int* in_sizes, int n_in,
                              void* d_out, int out_size, void* d_ws, size_t ws_size,
                              hipStream_t stream) {
  const float* x     = (const float*)d_in[0];
  const int*   label = (const int*)d_in[1];
  const int*   seqs  = (const int*)d_in[2];
  const int*   edge  = (const int*)d_in[3];
  const int*   ntype = (const int*)d_in[4];
  const float* fcW   = (const float*)d_in[5];
  const float* fcB   = (const float*)d_in[6];
  const float* gcnW  = (const float*)d_in[7];
  const float* gcnB  = (const float*)d_in[8];
  const float* predW = (const float*)d_in[12];
  const float* predB = (const float*)d_in[13];

  const int n = in_sizes[0] / 128;          // 50000
  const int e = in_sizes[3] / 2;            // 600000
  const int T = in_sizes[5] / (128 * 128);  // 4
  const int L = in_sizes[8] / 128;          // 2
  const int C = in_sizes[13];               // 16
  const int slen = 16;
  const int b_total = in_sizes[2] / slen;   // 2048

  const int* row = edge;
  const int* col = edge + e;

  char* ws = (char*)d_ws;
  const size_t node_bf = (size_t)n * 128 * sizeof(u16);
  u16*   gh      = (u16*)ws;                 ws += node_bf;
  u16*   xws     = (u16*)ws;                 ws += node_bf;
  u16*   wt      = (u16*)ws;                 ws += (size_t)(T + L) * 16384 * 2;
  float* dis     = (float*)ws;               ws += (size_t)n * 4;
  int*   ecnt    = (int*)ws;                 ws += (size_t)n * 4;
  int*   scanex  = (int*)ws;                 ws += (size_t)n * 4;
  int*   col_ptr = (int*)ws;                 ws += (size_t)(n + 16) * 4;
  int*   cursor  = (int*)ws;                 ws += (size_t)n * 4;
  int*   partial = (int*)ws;                 ws += 1024 * 4;
  int*   edge_row= (int*)ws;                 ws += (size_t)e * 4;

  float* out_logits = (float*)d_out;
  float* out_label  = out_logits + (size_t)b_total * C;

  const int nb = (n + NPB - 1) / NPB;
  const int nscan = (n + 255) / 256;
  const int wt_total = (T + L) * 16384;

  // weight transpose+cast (once), then node features
  hipLaunchKernelGGL(k_wt, dim3((wt_total + 255) / 256), dim3(256), 0, stream,
                     fcW, gcnW, wt, T, wt_total);
  hipLaunchKernelGGL(k_fc, dim3(nb), dim3(256), 0, stream, x, ntype, wt, fcB, gh, n);

  // CSR build (once)
  hipLaunchKernelGGL(k_zero, dim3(nscan), dim3(256), 0, stream, ecnt, n);
  hipLaunchKernelGGL(k_count, dim3((e + 255) / 256), dim3(256), 0, stream, col, ecnt, e);
  hipLaunchKernelGGL(k_scan1, dim3(nscan), dim3(256), 0, stream, ecnt, scanex, partial, n);
  hipLaunchKernelGGL(k_scan2, dim3(1), dim3(256), 0, stream, partial, nscan);
  hipLaunchKernelGGL(k_scan3, dim3(nscan), dim3(256), 0, stream, scanex, partial, ecnt,
                     col_ptr, cursor, dis, n, e);
  hipLaunchKernelGGL(k_fill, dim3((e + 255) / 256), dim3(256), 0, stream, row, col,
                     cursor, edge_row, e);

  for (int l = 0; l < L; ++l) {
    hipLaunchKernelGGL(k_gemm_scale, dim3(nb), dim3(256), 0, stream,
                       gh, wt + (size_t)(T + l) * 16384, dis, xws, n);
    hipLaunchKernelGGL(k_gather, dim3((n + 3) / 4), dim3(256), 0, stream,
                       col_ptr, edge_row, xws, dis, gcnB + (size_t)l * 128, gh, n);
  }
  hipLaunchKernelGGL(k_pred, dim3((b_total * C + 255) / 256), dim3(256), 0, stream,
                     gh, seqs, label, predW, predB, out_logits, out_label,
                     b_total, C, slen);
}

// Round 6
// 259.915 us; speedup vs baseline: 3.0494x; 1.0892x over previous
//
#include <hip/hip_runtime.h>
#include <hip/hip_bf16.h>

// ---------------------------------------------------------------------------
// HINormer forward, bf16+MFMA backbone (R6).
//   gh0 = x @ fcW[type] + fcB[type]          (MFMA, bf16 in / f32 acc)
//   dis = (1+in_deg)^-0.5
//   per layer: xws = (gh @ W)*dis (MFMA);  gh = relu((xws[c]+sum xws[row])*dis+b)
//   out0 = gh[ego] @ predW + predB ; out1 = (float)label[ego]
// R6 changes vs R5:
//  - NPB 64->128, B-fragments preloaded to regs: inner loop 8 ds_read : 16 MFMA
//    per k-slice (was 6:8), W-staging per node halved.
//  - Last-layer gather runs only over the 2048 ego nodes (output-dead rows
//    skipped), writing a compact gh2[2048][128].
// ---------------------------------------------------------------------------

typedef __attribute__((ext_vector_type(8))) short short8;   // 8 bf16
typedef __attribute__((ext_vector_type(4))) float f32x4;
typedef unsigned short u16;

__device__ __forceinline__ float bf2f(u16 u) {
  union { float f; unsigned int i; } v; v.i = (unsigned int)u << 16; return v.f;
}
__device__ __forceinline__ u16 f2bf(float f) {
  union { float f; unsigned int i; } v; v.f = f;
  return (u16)((v.i + 0x7FFF + ((v.i >> 16) & 1)) >> 16);
}

#define NPB 128  // nodes per GEMM block

// ---- weight pre-transpose: wt[m][d][k] = W[m][k][d] as bf16 ----------------
__global__ void k_wt(const float* __restrict__ fcW, const float* __restrict__ gcnW,
                     u16* __restrict__ wt, int T, int total) {
  int i = blockIdx.x * 256 + threadIdx.x;
  if (i >= total) return;
  int m = i >> 14;
  int dk = i & 16383;
  int d = dk >> 7, k = dk & 127;
  const float* src = (m < T) ? (fcW + ((size_t)m << 14)) : (gcnW + ((size_t)(m - T) << 14));
  wt[i] = f2bf(src[k * 128 + d]);
}

// smem: xs = 128x128 bf16 swizzled (32KB) ; wt = 128x128 bf16 swizzled (32KB)
#define SWZ(row, byte) ((byte) ^ (((row) & 15) << 4))

// stage a [128 x 128] bf16 tile (row stride 128) into swizzled LDS; rows >=
// rows_valid zero-filled. 256 threads: 2 threads/row, 128B each.
__device__ __forceinline__ void stage_tile_bf16(char* smem, const u16* __restrict__ gsrc,
                                                int rows_valid, int t) {
  int row = t >> 1;
  int h = (t & 1) * 64;
  int byte0 = row * 256 + h * 2;
  if (row < rows_valid) {
    const u16* src = gsrc + (size_t)row * 128 + h;
#pragma unroll
    for (int j = 0; j < 8; ++j) {
      short8 v = *(const short8*)(src + j * 8);
      *(short8*)(smem + SWZ(row, byte0 + j * 16)) = v;
    }
  } else {
    short8 z = (short8){0, 0, 0, 0, 0, 0, 0, 0};
#pragma unroll
    for (int j = 0; j < 8; ++j)
      *(short8*)(smem + SWZ(row, byte0 + j * 16)) = z;
  }
}

// 4 waves; wave w covers output cols [w*32, w*32+32). B preloaded (32 VGPR),
// A streamed from LDS: per k-slice 8 ds_read_b128 : 16 MFMA.
__device__ __forceinline__ void mfma_core128(const char* xs, const char* wt, int t,
                                             f32x4 acc[8][2]) {
  const int lane = t & 63, w = t >> 6;
  const int lr = lane & 15, lk = lane >> 4;
  short8 bfrag[4][2];
#pragma unroll
  for (int ks = 0; ks < 4; ++ks) {
    int kb = ks * 64 + lk * 16;
#pragma unroll
    for (int ch = 0; ch < 2; ++ch) {
      int row = w * 32 + ch * 16 + lr;
      bfrag[ks][ch] = *(const short8*)(wt + SWZ(row, row * 256 + kb));
    }
  }
#pragma unroll
  for (int ks = 0; ks < 4; ++ks) {
    int kb = ks * 64 + lk * 16;
    short8 a[8];
#pragma unroll
    for (int rg = 0; rg < 8; ++rg) {
      int row = rg * 16 + lr;
      a[rg] = *(const short8*)(xs + SWZ(row, row * 256 + kb));
    }
#pragma unroll
    for (int rg = 0; rg < 8; ++rg)
#pragma unroll
      for (int ch = 0; ch < 2; ++ch)
        acc[rg][ch] = __builtin_amdgcn_mfma_f32_16x16x32_bf16(a[rg], bfrag[ks][ch],
                                                              acc[rg][ch], 0, 0, 0);
  }
}

// ---- k_fc: x(f32) @ fcW[type] + fcB ; out gh bf16 --------------------------
// Mixed-type tiles (<=3 of 391): loop over the tile's type range, full MFMA
// each, masked writeback.
__global__ __launch_bounds__(256) void k_fc(const float* __restrict__ x,
                                            const int* __restrict__ node_type,
                                            const u16* __restrict__ wt_fc,  // [T][128][128]
                                            const float* __restrict__ fcB,
                                            u16* __restrict__ gh, int n_nodes) {
  __shared__ char smem[65536];
  char* smem_xs = smem;
  char* smem_wt = smem + 32768;
  const int t = threadIdx.x;
  const int nbase = blockIdx.x * NPB;
  const int nend = min(nbase + NPB, n_nodes);
  const int t0 = node_type[nbase];
  const int t1 = node_type[nend - 1];   // sorted types -> tile covers [t0,t1]

  // stage x tile -> bf16 swizzled LDS (f32 source, convert)
  {
    int row = t >> 1;
    int h = (t & 1) * 64;
    int node = nbase + row;
    int byte0 = row * 256 + h * 2;
    if (node < n_nodes) {
      const float4* src = (const float4*)(x + (size_t)node * 128 + h);
#pragma unroll
      for (int j = 0; j < 8; ++j) {
        float4 a4 = src[j * 2], b4 = src[j * 2 + 1];
        u16 tmp[8] = {f2bf(a4.x), f2bf(a4.y), f2bf(a4.z), f2bf(a4.w),
                      f2bf(b4.x), f2bf(b4.y), f2bf(b4.z), f2bf(b4.w)};
        *(short8*)(smem_xs + SWZ(row, byte0 + j * 16)) = *(short8*)tmp;
      }
    } else {
      short8 z = (short8){0, 0, 0, 0, 0, 0, 0, 0};
#pragma unroll
      for (int j = 0; j < 8; ++j)
        *(short8*)(smem_xs + SWZ(row, byte0 + j * 16)) = z;
    }
  }

  const int lane = t & 63, w = t >> 6;
  const int lr = lane & 15, lk = lane >> 4;

  for (int tt = t0; tt <= t1; ++tt) {
    if (tt > t0) __syncthreads();  // drain prior-iteration smem_wt reads
    stage_tile_bf16(smem_wt, wt_fc + ((size_t)tt << 14), 128, t);
    __syncthreads();

    f32x4 acc[8][2];
#pragma unroll
    for (int rg = 0; rg < 8; ++rg)
#pragma unroll
      for (int ch = 0; ch < 2; ++ch) acc[rg][ch] = (f32x4){0.f, 0.f, 0.f, 0.f};
    mfma_core128(smem_xs, smem_wt, t, acc);

    float bv0 = fcB[tt * 128 + w * 32 + lr];
    float bv1 = fcB[tt * 128 + w * 32 + 16 + lr];
#pragma unroll
    for (int rg = 0; rg < 8; ++rg) {
#pragma unroll
      for (int reg = 0; reg < 4; ++reg) {
        int node = nbase + rg * 16 + lk * 4 + reg;
        if (node < n_nodes && node_type[node] == tt) {
          gh[(size_t)node * 128 + w * 32 + lr]      = f2bf(acc[rg][0][reg] + bv0);
          gh[(size_t)node * 128 + w * 32 + 16 + lr] = f2bf(acc[rg][1][reg] + bv1);
        }
      }
    }
  }
}

// ---- k_gemm_scale: xws = (gh @ W) * dis ; bf16 in/out ----------------------
__global__ __launch_bounds__(256) void k_gemm_scale(const u16* __restrict__ ghin,
                                                    const u16* __restrict__ wtg,  // [128][128]
                                                    const float* __restrict__ dis,
                                                    u16* __restrict__ xws, int n_nodes) {
  __shared__ char smem[65536];
  char* smem_xs = smem;
  char* smem_wt = smem + 32768;
  const int t = threadIdx.x;
  const int nbase = blockIdx.x * NPB;

  stage_tile_bf16(smem_xs, ghin + (size_t)nbase * 128,
                  min(n_nodes - nbase, NPB), t);
  stage_tile_bf16(smem_wt, wtg, 128, t);
  __syncthreads();

  f32x4 acc[8][2];
#pragma unroll
  for (int rg = 0; rg < 8; ++rg)
#pragma unroll
    for (int ch = 0; ch < 2; ++ch) acc[rg][ch] = (f32x4){0.f, 0.f, 0.f, 0.f};
  mfma_core128(smem_xs, smem_wt, t, acc);

  const int lane = t & 63, w = t >> 6;
  const int lr = lane & 15, lk = lane >> 4;
#pragma unroll
  for (int rg = 0; rg < 8; ++rg) {
#pragma unroll
    for (int reg = 0; reg < 4; ++reg) {
      int node = nbase + rg * 16 + lk * 4 + reg;
      if (node < n_nodes) {
        float s = dis[node];
        xws[(size_t)node * 128 + w * 32 + lr]      = f2bf(acc[rg][0][reg] * s);
        xws[(size_t)node * 128 + w * 32 + 16 + lr] = f2bf(acc[rg][1][reg] * s);
      }
    }
  }
}

// ---- CSR build --------------------------------------------------------------
__global__ void k_zero(int* __restrict__ p, int n) {
  int i = blockIdx.x * 256 + threadIdx.x;
  if (i < n) p[i] = 0;
}

__global__ void k_count(const int* __restrict__ col, int* __restrict__ ecnt, int e) {
  int i = blockIdx.x * 256 + threadIdx.x;
  if (i < e) atomicAdd(&ecnt[col[i]], 1);
}

__global__ __launch_bounds__(256) void k_scan1(const int* __restrict__ ecnt,
                                               int* __restrict__ scanex,
                                               int* __restrict__ partials, int n) {
  __shared__ int s[256];
  const int t = threadIdx.x;
  const int i = blockIdx.x * 256 + t;
  int v = (i < n) ? ecnt[i] : 0;
  s[t] = v;
  __syncthreads();
  for (int off = 1; off < 256; off <<= 1) {
    int add = (t >= off) ? s[t - off] : 0;
    __syncthreads();
    s[t] += add;
    __syncthreads();
  }
  if (i < n) scanex[i] = s[t] - v;
  if (t == 255) partials[blockIdx.x] = s[t];
}

__global__ __launch_bounds__(256) void k_scan2(int* __restrict__ partials, int np) {
  __shared__ int s[256];
  const int t = threadIdx.x;
  int v = (t < np) ? partials[t] : 0;
  s[t] = v;
  __syncthreads();
  for (int off = 1; off < 256; off <<= 1) {
    int add = (t >= off) ? s[t - off] : 0;
    __syncthreads();
    s[t] += add;
    __syncthreads();
  }
  if (t < np) partials[t] = s[t] - v;  // exclusive
}

__global__ void k_scan3(const int* __restrict__ scanex, const int* __restrict__ partials,
                        const int* __restrict__ ecnt, int* __restrict__ col_ptr,
                        int* __restrict__ cursor, float* __restrict__ dis,
                        int n, int e_total) {
  int i = blockIdx.x * 256 + threadIdx.x;
  if (i < n) {
    int p = scanex[i] + partials[i >> 8];
    col_ptr[i] = p;
    cursor[i] = p;
    dis[i] = rsqrtf((float)(ecnt[i] + 1));
  }
  if (i == 0) col_ptr[n] = e_total;
}

__global__ void k_fill(const int* __restrict__ row, const int* __restrict__ col,
                       int* __restrict__ cursor, int* __restrict__ edge_row, int e) {
  int i = blockIdx.x * 256 + threadIdx.x;
  if (i < e) {
    int c = col[i];
    int pos = atomicAdd(&cursor[c], 1);
    edge_row[pos] = row[i];
  }
}

// ---- fused gather + finalize: 1 wave/node, 4 edges in flight ---------------
__device__ __forceinline__ void gather_node(int node, const int* __restrict__ col_ptr,
                                            const int* __restrict__ edge_row,
                                            const u16* __restrict__ xws,
                                            const float* __restrict__ dis,
                                            const float* __restrict__ bias,
                                            u16* __restrict__ dst, int lane) {
  const int g = lane & 15;   // elem group: elems g*8 .. g*8+7
  const int s = lane >> 4;   // edge slot 0..3
  float acc[8] = {0.f, 0.f, 0.f, 0.f, 0.f, 0.f, 0.f, 0.f};
  if (s == 0) {  // self loop term
    short8 v = *(const short8*)(xws + (size_t)node * 128 + g * 8);
#pragma unroll
    for (int j = 0; j < 8; ++j) acc[j] = bf2f((u16)v[j]);
  }
  const int e0 = col_ptr[node], e1 = col_ptr[node + 1];
  for (int e = e0 + s; e < e1; e += 4) {
    int r = edge_row[e];
    short8 v = *(const short8*)(xws + (size_t)r * 128 + g * 8);
#pragma unroll
    for (int j = 0; j < 8; ++j) acc[j] += bf2f((u16)v[j]);
  }
#pragma unroll
  for (int j = 0; j < 8; ++j) {
    acc[j] += __shfl_xor(acc[j], 16);
    acc[j] += __shfl_xor(acc[j], 32);
  }
  if (s == 0) {
    float ds = dis[node];
    u16 o[8];
#pragma unroll
    for (int j = 0; j < 8; ++j)
      o[j] = f2bf(fmaxf(acc[j] * ds + bias[g * 8 + j], 0.f));
    *(short8*)(dst + g * 8) = *(short8*)o;
  }
}

__global__ __launch_bounds__(256) void k_gather(const int* __restrict__ col_ptr,
                                                const int* __restrict__ edge_row,
                                                const u16* __restrict__ xws,
                                                const float* __restrict__ dis,
                                                const float* __restrict__ bias,
                                                u16* __restrict__ gh, int n_nodes) {
  const int t = threadIdx.x;
  const int node = blockIdx.x * 4 + (t >> 6);
  if (node >= n_nodes) return;
  gather_node(node, col_ptr, edge_row, xws, dis, bias,
              gh + (size_t)node * 128, t & 63);
}

// last layer: only ego rows are consumed downstream
__global__ __launch_bounds__(256) void k_gather_ego(const int* __restrict__ col_ptr,
                                                    const int* __restrict__ edge_row,
                                                    const u16* __restrict__ xws,
                                                    const float* __restrict__ dis,
                                                    const float* __restrict__ bias,
                                                    const int* __restrict__ seqs,
                                                    u16* __restrict__ gh2,
                                                    int b_total, int slen) {
  const int t = threadIdx.x;
  const int b = blockIdx.x * 4 + (t >> 6);
  if (b >= b_total) return;
  int node = seqs[(size_t)b * slen];
  gather_node(node, col_ptr, edge_row, xws, dis, bias,
              gh2 + (size_t)b * 128, t & 63);
}

__global__ void k_pred(const u16* __restrict__ gh2, const int* __restrict__ seqs,
                       const int* __restrict__ label, const float* __restrict__ predW,
                       const float* __restrict__ predB, float* __restrict__ out,
                       float* __restrict__ out_label, int b_total, int n_classes,
                       int slen) {
  int tid = blockIdx.x * 256 + threadIdx.x;
  int b = tid / n_classes;
  if (b >= b_total) return;
  int c = tid - b * n_classes;
  const u16* g = gh2 + (size_t)b * 128;
  float s = predB[c];
#pragma unroll 8
  for (int i = 0; i < 128; ++i) s += bf2f(g[i]) * predW[i * n_classes + c];
  out[(size_t)b * n_classes + c] = s;
  if (c == 0) out_label[b] = (float)label[seqs[(size_t)b * slen]];
}

extern "C" void kernel_launch(void* const* d_in, const int* in_sizes, int n_in,
                              void* d_out, int out_size, void* d_ws, size_t ws_size,
                              hipStream_t stream) {
  const float* x     = (const float*)d_in[0];
  const int*   label = (const int*)d_in[1];
  const int*   seqs  = (const int*)d_in[2];
  const int*   edge  = (const int*)d_in[3];
  const int*   ntype = (const int*)d_in[4];
  const float* fcW   = (const float*)d_in[5];
  const float* fcB   = (const float*)d_in[6];
  const float* gcnW  = (const float*)d_in[7];
  const float* gcnB  = (const float*)d_in[8];
  const float* predW = (const float*)d_in[12];
  const float* predB = (const float*)d_in[13];

  const int n = in_sizes[0] / 128;          // 50000
  const int e = in_sizes[3] / 2;            // 600000
  const int T = in_sizes[5] / (128 * 128);  // 4
  const int L = in_sizes[8] / 128;          // 2
  const int C = in_sizes[13];               // 16
  const int slen = 16;
  const int b_total = in_sizes[2] / slen;   // 2048

  const int* row = edge;
  const int* col = edge + e;

  char* ws = (char*)d_ws;
  const size_t node_bf = (size_t)n * 128 * sizeof(u16);
  u16*   gh      = (u16*)ws;                 ws += node_bf;
  u16*   xws     = (u16*)ws;                 ws += node_bf;
  u16*   gh2     = (u16*)ws;                 ws += (size_t)b_total * 128 * 2;
  u16*   wt      = (u16*)ws;                 ws += (size_t)(T + L) * 16384 * 2;
  float* dis     = (float*)ws;               ws += (size_t)n * 4;
  int*   ecnt    = (int*)ws;                 ws += (size_t)n * 4;
  int*   scanex  = (int*)ws;                 ws += (size_t)n * 4;
  int*   col_ptr = (int*)ws;                 ws += (size_t)(n + 16) * 4;
  int*   cursor  = (int*)ws;                 ws += (size_t)n * 4;
  int*   partial = (int*)ws;                 ws += 1024 * 4;
  int*   edge_row= (int*)ws;                 ws += (size_t)e * 4;

  float* out_logits = (float*)d_out;
  float* out_label  = out_logits + (size_t)b_total * C;

  const int nb = (n + NPB - 1) / NPB;       // 391
  const int nscan = (n + 255) / 256;        // 196
  const int wt_total = (T + L) * 16384;

  // weight transpose+cast (once), then node features
  hipLaunchKernelGGL(k_wt, dim3((wt_total + 255) / 256), dim3(256), 0, stream,
                     fcW, gcnW, wt, T, wt_total);
  hipLaunchKernelGGL(k_fc, dim3(nb), dim3(256), 0, stream, x, ntype, wt, fcB, gh, n);

  // CSR build (once)
  hipLaunchKernelGGL(k_zero, dim3(nscan), dim3(256), 0, stream, ecnt, n);
  hipLaunchKernelGGL(k_count, dim3((e + 255) / 256), dim3(256), 0, stream, col, ecnt, e);
  hipLaunchKernelGGL(k_scan1, dim3(nscan), dim3(256), 0, stream, ecnt, scanex, partial, n);
  hipLaunchKernelGGL(k_scan2, dim3(1), dim3(256), 0, stream, partial, nscan);
  hipLaunchKernelGGL(k_scan3, dim3(nscan), dim3(256), 0, stream, scanex, partial, ecnt,
                     col_ptr, cursor, dis, n, e);
  hipLaunchKernelGGL(k_fill, dim3((e + 255) / 256), dim3(256), 0, stream, row, col,
                     cursor, edge_row, e);

  for (int l = 0; l < L; ++l) {
    hipLaunchKernelGGL(k_gemm_scale, dim3(nb), dim3(256), 0, stream,
                       gh, wt + (size_t)(T + l) * 16384, dis, xws, n);
    if (l < L - 1) {
      hipLaunchKernelGGL(k_gather, dim3((n + 3) / 4), dim3(256), 0, stream,
                         col_ptr, edge_row, xws, dis, gcnB + (size_t)l * 128, gh, n);
    } else {
      hipLaunchKernelGGL(k_gather_ego, dim3((b_total + 3) / 4), dim3(256), 0, stream,
                         col_ptr, edge_row, xws, dis, gcnB + (size_t)l * 128,
                         seqs, gh2, b_total, slen);
    }
  }
  hipLaunchKernelGGL(k_pred, dim3((b_total * C + 255) / 256), dim3(256), 0, stream,
                     gh2, seqs, label, predW, predB, out_logits, out_label,
                     b_total, C, slen);
}